// Round 1
// baseline (240.143 us; speedup 1.0000x reference)
//
#include <hip/hip_runtime.h>
#include <stdint.h>

#define BATCH 32
#define TLEN  1024
#define DIN   512
#define DOUT  512
#define KW    5
#define TOUT  1020          // TLEN - KW + 1
#define KDIM  (DIN * KW)    // 2560

#define BM 128
#define BN 128
#define BK 32

typedef __attribute__((ext_vector_type(8))) short bf16x8;
typedef __attribute__((ext_vector_type(4))) float f32x4;

__device__ __forceinline__ uint16_t f2bf(float f) {
    uint32_t u = __float_as_uint(f);
    uint32_t r = u + 0x7FFFu + ((u >> 16) & 1u);   // RNE to bf16
    return (uint16_t)(r >> 16);
}

// x: [B,T,DIN] fp32 -> xb bf16, 8 elements/thread, exact grid (no guard)
__global__ void convert_x(const float4* __restrict__ x, uint4* __restrict__ xb) {
    int idx = blockIdx.x * blockDim.x + threadIdx.x;   // 0 .. 2097151
    float4 a = x[2 * idx];
    float4 b = x[2 * idx + 1];
    uint4 v;
    v.x = (uint32_t)f2bf(a.x) | ((uint32_t)f2bf(a.y) << 16);
    v.y = (uint32_t)f2bf(a.z) | ((uint32_t)f2bf(a.w) << 16);
    v.z = (uint32_t)f2bf(b.x) | ((uint32_t)f2bf(b.y) << 16);
    v.w = (uint32_t)f2bf(b.z) | ((uint32_t)f2bf(b.w) << 16);
    xb[idx] = v;
}

// W [DOUT,DIN,KW] fp32 -> Wb [DOUT][KDIM] bf16 with Wb[o][k*512+i] = W[o,i,k]
__global__ void pack_w(const float* __restrict__ w, uint16_t* __restrict__ wb) {
    int idx = blockIdx.x * blockDim.x + threadIdx.x;   // 0 .. 1310719 exact
    int o   = idx / KDIM;
    int rem = idx - o * KDIM;
    int k   = rem >> 9;          // /512
    int i   = rem & 511;
    wb[idx] = f2bf(w[(o * DIN + i) * KW + k]);
}

// GEMM: C[m=(b,t), n=o] = sum_kk xflat[b, t*512+kk] * Wb[n][kk]
__global__ void tdnn_gemm(const uint16_t* __restrict__ xb,
                          const uint16_t* __restrict__ wb,
                          const float* __restrict__ bias,
                          float* __restrict__ out) {
    __shared__ uint16_t As[BM * BK];   // [m][k] row-major, 8 KB
    __shared__ uint16_t Bs[BN * BK];   // [n][k] row-major, 8 KB

    const int tile = blockIdx.x;       // 0..1023
    const int nb   = tile & 3;         // 4 N tiles
    const int tb   = (tile >> 2) & 7;  // 8 T tiles
    const int b    = tile >> 5;        // 32 batches
    const int t0   = tb * BM;
    const int n0   = nb * BN;

    const int tid  = threadIdx.x;
    const int lane = tid & 63;
    const int w    = tid >> 6;         // wave 0..3
    const int m_wave = (w & 1) * 64;
    const int n_wave = (w >> 1) * 64;

    const uint16_t* xrow = xb + (size_t)b * TLEN * DIN + (size_t)t0 * DIN;

    f32x4 acc[4][4] = {};

    const int ml = lane & 15;
    const int kq = (lane >> 4) * 8;

    for (int kb = 0; kb < KDIM; kb += BK) {
        // ---- stage A: 128 rows x 32 bf16 (64 B/row), lane-contiguous LDS ----
        #pragma unroll
        for (int i = 0; i < 2; ++i) {
            int c   = w * 128 + i * 64 + lane;     // 16B chunk id
            int row = c >> 2;
            int cc  = c & 3;
            const uint16_t* gp = xrow + row * DIN + kb + cc * 8;
            const uint16_t* lp = &As[(w * 128 + i * 64) * 8]; // wave-uniform base
            __builtin_amdgcn_global_load_lds(
                (const __attribute__((address_space(1))) void*)gp,
                (__attribute__((address_space(3))) void*)lp, 16, 0, 0);
        }
        // ---- stage B: 128 n-rows x 32 bf16 ----
        #pragma unroll
        for (int i = 0; i < 2; ++i) {
            int c   = w * 128 + i * 64 + lane;
            int row = c >> 2;
            int cc  = c & 3;
            const uint16_t* gp = wb + (size_t)(n0 + row) * KDIM + kb + cc * 8;
            const uint16_t* lp = &Bs[(w * 128 + i * 64) * 8];
            __builtin_amdgcn_global_load_lds(
                (const __attribute__((address_space(1))) void*)gp,
                (__attribute__((address_space(3))) void*)lp, 16, 0, 0);
        }
        __syncthreads();

        bf16x8 af[4], bfr[4];
        #pragma unroll
        for (int mi = 0; mi < 4; ++mi)
            af[mi] = *(const bf16x8*)&As[(m_wave + mi * 16 + ml) * BK + kq];
        #pragma unroll
        for (int ni = 0; ni < 4; ++ni)
            bfr[ni] = *(const bf16x8*)&Bs[(n_wave + ni * 16 + ml) * BK + kq];

        #pragma unroll
        for (int mi = 0; mi < 4; ++mi)
            #pragma unroll
            for (int ni = 0; ni < 4; ++ni)
                acc[mi][ni] = __builtin_amdgcn_mfma_f32_16x16x32_bf16(
                    af[mi], bfr[ni], acc[mi][ni], 0, 0, 0);
        __syncthreads();
    }

    // ---- epilogue: C[row=t, col=o]; D map: col=lane&15, row=(lane>>4)*4+r ----
    const int rq = (lane >> 4) * 4;
    #pragma unroll
    for (int ni = 0; ni < 4; ++ni) {
        int o = n0 + n_wave + ni * 16 + ml;
        float bv = bias[o];
        float* orow = out + ((size_t)b * DOUT + o) * TOUT;
        #pragma unroll
        for (int mi = 0; mi < 4; ++mi) {
            int tbase = t0 + m_wave + mi * 16 + rq;
            #pragma unroll
            for (int r = 0; r < 4; ++r) {
                int t = tbase + r;
                if (t < TOUT) {
                    float v = acc[mi][ni][r] + bv;
                    orow[t] = v > 0.0f ? v : 0.0f;
                }
            }
        }
    }
}

extern "C" void kernel_launch(void* const* d_in, const int* in_sizes, int n_in,
                              void* d_out, int out_size, void* d_ws, size_t ws_size,
                              hipStream_t stream) {
    const float* x    = (const float*)d_in[0];
    const float* wgt  = (const float*)d_in[1];
    const float* bias = (const float*)d_in[2];
    float* out = (float*)d_out;

    // ws layout: xb first (so the b=31 tail over-read lands in wb, not OOB)
    uint16_t* xb = (uint16_t*)d_ws;                                   // 33.55 MB
    uint16_t* wb = (uint16_t*)((char*)d_ws + (size_t)BATCH * TLEN * DIN * 2);

    convert_x<<<8192, 256, 0, stream>>>((const float4*)x, (uint4*)xb);
    pack_w<<<5120, 256, 0, stream>>>(wgt, wb);
    tdnn_gemm<<<1024, 256, 0, stream>>>(xb, wb, bias, out);
}

// Round 2
// 203.042 us; speedup vs baseline: 1.1827x; 1.1827x over previous
//
#include <hip/hip_runtime.h>
#include <stdint.h>

#define BATCH 32
#define TLEN  1024
#define DIN   512
#define DOUT  512
#define KW    5
#define TOUT  1020          // TLEN - KW + 1
#define KDIM  (DIN * KW)    // 2560

#define BM 128
#define BN 128
#define BK 64               // 128-B LDS rows; XOR-swizzled chunks

typedef __attribute__((ext_vector_type(8))) short bf16x8;
typedef __attribute__((ext_vector_type(4))) float f32x4;

__device__ __forceinline__ uint16_t f2bf(float f) {
    uint32_t u = __float_as_uint(f);
    uint32_t r = u + 0x7FFFu + ((u >> 16) & 1u);   // RNE to bf16
    return (uint16_t)(r >> 16);
}

// Fused: blocks [0,8192) convert x fp32->bf16 (8 elem/thread);
//        blocks [8192,13312) pack W [DOUT,DIN,KW] -> Wb[o][k*512+i] bf16.
__global__ void convert_pack(const float4* __restrict__ x, uint4* __restrict__ xb,
                             const float* __restrict__ w, uint16_t* __restrict__ wb) {
    int bid = blockIdx.x;
    if (bid < 8192) {
        int idx = bid * 256 + threadIdx.x;          // 0 .. 2097151 exact
        float4 a = x[2 * idx];
        float4 b = x[2 * idx + 1];
        uint4 v;
        v.x = (uint32_t)f2bf(a.x) | ((uint32_t)f2bf(a.y) << 16);
        v.y = (uint32_t)f2bf(a.z) | ((uint32_t)f2bf(a.w) << 16);
        v.z = (uint32_t)f2bf(b.x) | ((uint32_t)f2bf(b.y) << 16);
        v.w = (uint32_t)f2bf(b.z) | ((uint32_t)f2bf(b.w) << 16);
        xb[idx] = v;
    } else {
        int idx = (bid - 8192) * 256 + threadIdx.x; // 0 .. 1310719 exact
        int o   = idx / KDIM;
        int rem = idx - o * KDIM;
        int k   = rem >> 9;
        int i   = rem & 511;
        wb[idx] = f2bf(w[(o * DIN + i) * KW + k]);
    }
}

// GEMM: C[m=(b,t), n=o] = sum_k xflat[b, t*512+k] * Wb[n][k]
// LDS rows are 128 B (32 banks); chunk j of row r holds global chunk j^(r&7)
// so 16-lane fragment groups stride all 32 banks (2-way alias = free).
__global__ void __launch_bounds__(256, 4)
tdnn_gemm(const uint16_t* __restrict__ xb,
          const uint16_t* __restrict__ wb,
          const float* __restrict__ bias,
          float* __restrict__ out) {
    __shared__ uint16_t As[BM * BK];   // 16 KB
    __shared__ uint16_t Bs[BN * BK];   // 16 KB

    // XCD-aware swizzle: j = xcd + 8*nb + 32*gi ; group g=(b,tb)=gi*8+xcd.
    // The 4 nb-blocks of one A-tile differ by 8 -> same XCD, adjacent in time.
    const int j    = blockIdx.x;       // 0..1023
    const int xcd  = j & 7;
    const int nb   = (j >> 3) & 3;
    const int gi   = j >> 5;           // 0..31
    const int g    = gi * 8 + xcd;     // 0..255
    const int b    = g >> 3;
    const int tb   = g & 7;
    const int t0   = tb * BM;
    const int n0   = nb * BN;

    const int tid  = threadIdx.x;
    const int lane = tid & 63;
    const int w    = tid >> 6;
    const int m_wave = (w & 1) * 64;
    const int n_wave = (w >> 1) * 64;

    const uint16_t* xrow = xb + (size_t)b * TLEN * DIN + (size_t)t0 * DIN;
    const uint16_t* wrow = wb + (size_t)n0 * KDIM;

    f32x4 acc[4][4] = {};

    const int ml = lane & 15;
    const int kg = lane >> 4;          // 0..3 fragment chunk group

    for (int kb = 0; kb < KDIM; kb += BK) {
        // ---- stage A: 128 rows x 128 B = 1024 chunks of 16 B ----
        #pragma unroll
        for (int i = 0; i < 4; ++i) {
            int c    = w * 256 + i * 64 + lane;
            int row  = c >> 3;
            int slot = c & 7;
            int ccg  = slot ^ (row & 7);
            const uint16_t* gp = xrow + row * DIN + kb + ccg * 8;
            const uint16_t* lp = &As[(w * 256 + i * 64) * 8];  // wave-uniform base
            __builtin_amdgcn_global_load_lds(
                (const __attribute__((address_space(1))) void*)gp,
                (__attribute__((address_space(3))) void*)lp, 16, 0, 0);
        }
        // ---- stage B ----
        #pragma unroll
        for (int i = 0; i < 4; ++i) {
            int c    = w * 256 + i * 64 + lane;
            int row  = c >> 3;
            int slot = c & 7;
            int ccg  = slot ^ (row & 7);
            const uint16_t* gp = wrow + (size_t)row * KDIM + kb + ccg * 8;
            const uint16_t* lp = &Bs[(w * 256 + i * 64) * 8];
            __builtin_amdgcn_global_load_lds(
                (const __attribute__((address_space(1))) void*)gp,
                (__attribute__((address_space(3))) void*)lp, 16, 0, 0);
        }
        __syncthreads();

        #pragma unroll
        for (int h = 0; h < 2; ++h) {
            const int cc = h * 4 + kg;          // global 16B-chunk within row
            bf16x8 af[4], bfr[4];
            #pragma unroll
            for (int mi = 0; mi < 4; ++mi) {
                int r = m_wave + mi * 16 + ml;
                af[mi] = *(const bf16x8*)&As[r * BK + (cc ^ (r & 7)) * 8];
            }
            #pragma unroll
            for (int ni = 0; ni < 4; ++ni) {
                int r = n_wave + ni * 16 + ml;
                bfr[ni] = *(const bf16x8*)&Bs[r * BK + (cc ^ (r & 7)) * 8];
            }
            #pragma unroll
            for (int mi = 0; mi < 4; ++mi)
                #pragma unroll
                for (int ni = 0; ni < 4; ++ni)
                    acc[mi][ni] = __builtin_amdgcn_mfma_f32_16x16x32_bf16(
                        af[mi], bfr[ni], acc[mi][ni], 0, 0, 0);
        }
        __syncthreads();
    }

    // ---- epilogue: D map: col=lane&15, row=(lane>>4)*4+r ----
    const int rq = (lane >> 4) * 4;
    #pragma unroll
    for (int ni = 0; ni < 4; ++ni) {
        int o = n0 + n_wave + ni * 16 + ml;
        float bv = bias[o];
        float* orow = out + ((size_t)b * DOUT + o) * TOUT;
        #pragma unroll
        for (int mi = 0; mi < 4; ++mi) {
            int tbase = t0 + m_wave + mi * 16 + rq;
            #pragma unroll
            for (int r = 0; r < 4; ++r) {
                int t = tbase + r;
                if (t < TOUT) {
                    float v = acc[mi][ni][r] + bv;
                    orow[t] = v > 0.0f ? v : 0.0f;
                }
            }
        }
    }
}

extern "C" void kernel_launch(void* const* d_in, const int* in_sizes, int n_in,
                              void* d_out, int out_size, void* d_ws, size_t ws_size,
                              hipStream_t stream) {
    const float* x    = (const float*)d_in[0];
    const float* wgt  = (const float*)d_in[1];
    const float* bias = (const float*)d_in[2];
    float* out = (float*)d_out;

    // ws layout: xb first (b=31 tail over-read lands in wb, not OOB)
    uint16_t* xb = (uint16_t*)d_ws;                                   // 33.55 MB
    uint16_t* wb = (uint16_t*)((char*)d_ws + (size_t)BATCH * TLEN * DIN * 2);

    convert_pack<<<13312, 256, 0, stream>>>((const float4*)x, (uint4*)xb, wgt, wb);
    tdnn_gemm<<<1024, 256, 0, stream>>>(xb, wb, bias, out);
}